// Round 3
// baseline (710.189 us; speedup 1.0000x reference)
//
#include <hip/hip_runtime.h>

#define H    128
#define T    512
#define DX   4
#define BB   220
#define SAMP 10
#define NS   (BB*SAMP)
#define M    16       // sequences per block
#define HSTR 168      // hbuf row stride in halves (336 B, 16B-aligned)
#define NBLK 14       // ceil(220/16)

typedef _Float16 half8 __attribute__((ext_vector_type(8)));
typedef float    f32x4 __attribute__((ext_vector_type(4)));

// workspace layout (fp32 elements)
#define WS_TEMB 0
#define WS_AEMB (WS_TEMB + BB*H)
#define WS_FEMB (WS_AEMB + BB*H)
#define WS_TA   (WS_FEMB + BB*H)
#define WS_TF   (WS_TA + NS*H)
#define WS_AN   (WS_TF + NS*H)
#define WS_FA   (WS_AN + NS*H)
#define WS_FLAGS (WS_FA + NS*H)   // 2 ints: [0]=floats-are-bf16, [1]=ints-are-int64

__device__ static inline float bf2f(unsigned short u) {
  unsigned int i = ((unsigned int)u) << 16;
  return __builtin_bit_cast(float, i);
}
__device__ static inline unsigned short f2bf(float f) {
  unsigned int i = __builtin_bit_cast(unsigned int, f);
  i += 0x7fffu + ((i >> 16) & 1u);
  return (unsigned short)(i >> 16);
}
__device__ static inline float loadF(const void* p, size_t i, int isbf) {
  return isbf ? bf2f(((const unsigned short*)p)[i]) : ((const float*)p)[i];
}
__device__ static inline int loadI(const void* p, int i, int is64) {
  return is64 ? (int)((const unsigned int*)p)[2*(size_t)i] : ((const int*)p)[i];
}
__device__ static inline float frcp(float x) { return __builtin_amdgcn_rcpf(x); }
__device__ static inline float sigm(float x) { return frcp(1.f + __expf(-x)); }
__device__ static inline float tanhx(float x) { return 1.f - 2.f*frcp(1.f + __expf(2.f*x)); }
__device__ static inline float scrub(float x) { return (x == x) ? x : 0.f; }
__device__ static inline int clampT(int v) { v = v - 1; if (v < 0) v = 0; if (v > T-1) v = T-1; return v; }

__global__ __launch_bounds__(256, 1) void lstm_scan(
    const void* __restrict__ x0_, const void* __restrict__ len0,
    const void* __restrict__ sub_ta, const void* __restrict__ sub_tf,
    const void* __restrict__ x1_, const void* __restrict__ len1,
    const void* __restrict__ sub_an,
    const void* __restrict__ x2_, const void* __restrict__ len2,
    const void* __restrict__ sub_fa,
    const void* __restrict__ Wih, const void* __restrict__ Whh,
    const void* __restrict__ bih, const void* __restrict__ bhh,
    float* __restrict__ ws)
{
  const int e      = blockIdx.y;
  const int s0     = blockIdx.x * M;
  const int nvalid = (BB - s0) < M ? (BB - s0) : M;
  const int tid    = threadIdx.x;
  const int lane   = tid & 63;
  const int w      = tid >> 6;     // wave 0..3, owns col-groups {2w, 2w+1}
  const int lo     = lane & 15;
  const int quad   = lane >> 4;

  // ---- in-block dtype detection (uniform scalar loop; block (0,0) publishes for dists)
  int fbf, f64;
  {
    const unsigned int* wp = (const unsigned int*)Whh;
    int cnt = 0;
    for (int i = 0; i < 64; ++i) {
      unsigned int lo16 = wp[i] & 0xFFFFu;
      int ex = (int)((lo16 >> 7) & 0xFFu);
      cnt += (ex >= 100 && ex <= 130);
    }
    fbf = (cnt >= 40);
    const unsigned int* l = (const unsigned int*)len0;
    f64 = ((l[1] | l[3] | l[5] | l[7]) == 0u);
    if (blockIdx.x == 0 && blockIdx.y == 0 && tid == 0) {
      int* fo = (int*)(ws + WS_FLAGS); fo[0] = fbf; fo[1] = f64;
    }
  }

  const void* xin  = (e==0) ? x0_ : (e==1 ? x1_ : x2_);
  const void* lenp = (e==0) ? len0 : (e==1 ? len1 : len2);

  __shared__ __align__(16) _Float16 hbuf[2][M][HSTR];  // h'(t) double-buffered, K=160 used
  __shared__ unsigned int xb[M][T+1];                  // f16x2 packed x, stride 513

  // ---- zero both h buffers (2*M*HSTR halves = M*HSTR uints)
  {
    unsigned int* hz = (unsigned int*)hbuf;
    for (int i = tid; i < M*HSTR; i += 256) hz[i] = 0u;
  }
  // ---- stage x[:, :, 0:2] to LDS as f16 pairs
  for (int i = tid; i < M*T; i += 256) {
    int m = i >> 9, t = i & (T-1);
    unsigned int v = 0u;
    if (m < nvalid) {
      size_t base = ((size_t)(s0+m)*T + t) * DX;
      _Float16 ha = (_Float16)loadF(xin, base + 0, fbf);
      _Float16 hb = (_Float16)loadF(xin, base + 1, fbf);
      v = (unsigned int)__builtin_bit_cast(unsigned short, ha)
        | ((unsigned int)__builtin_bit_cast(unsigned short, hb) << 16);
    }
    xb[m][t] = v;
  }
  // ---- weight B-fragments: W' = [W_hh | W_ih | b_ih+b_hh | 0] as K=160, 2 col-groups/wave
  half8 Bf[4][2][5];
  #pragma unroll
  for (int q = 0; q < 4; ++q) {
    #pragma unroll
    for (int cgi = 0; cgi < 2; ++cgi) {
      const int g = q*128 + (2*w + cgi)*16 + lo;
      #pragma unroll
      for (int kt = 0; kt < 5; ++kt) {
        #pragma unroll
        for (int j = 0; j < 8; ++j) {
          const int k = kt*32 + quad*8 + j;
          float v;
          if      (k < 128)  v = loadF(Whh, (size_t)g*H + k, fbf);
          else if (k == 128) v = loadF(Wih, (size_t)g*2 + 0, fbf);
          else if (k == 129) v = loadF(Wih, (size_t)g*2 + 1, fbf);
          else if (k == 130) v = loadF(bih, g, fbf) + loadF(bhh, g, fbf);
          else               v = 0.f;
          Bf[q][cgi][kt][j] = (_Float16)v;
        }
      }
    }
  }
  // ---- per-thread watcher slots (2 per thread; e==0 needs up to 336)
  int myt[2] = {-1, -1}, mym[2] = {0, 0}, myo[2] = {0, 0};
  #pragma unroll
  for (int s = 0; s < 2; ++s) {
    int idx = tid + s*256;
    if (e == 0) {
      if (idx < nvalid*21) {
        int m = idx / 21, j = idx - m*21, sg = s0 + m;
        mym[s] = m;
        if (j == 0)       { myt[s] = clampT(loadI(lenp, sg, f64));            myo[s] = WS_TEMB + sg*H; }
        else if (j <= 10) { int k = sg*10 + (j-1);  myt[s] = clampT(loadI(sub_ta, k, f64)); myo[s] = WS_TA + k*H; }
        else              { int k = sg*10 + (j-11); myt[s] = clampT(loadI(sub_tf, k, f64)); myo[s] = WS_TF + k*H; }
      }
    } else if (s == 0) {
      if (idx < nvalid*11) {
        int m = idx / 11, j = idx - m*11, sg = s0 + m;
        mym[s] = m;
        if (j == 0) { myt[s] = clampT(loadI(lenp, sg, f64)); myo[s] = (e==1 ? WS_AEMB : WS_FEMB) + sg*H; }
        else {
          int k = sg*10 + (j-1);
          if (e == 1) { myt[s] = clampT(loadI(sub_an, k, f64)); myo[s] = WS_AN + k*H; }
          else        { myt[s] = clampT(loadI(sub_fa, k, f64)); myo[s] = WS_FA + k*H; }
        }
      }
    }
  }
  __syncthreads();
  // ---- constant-1 column + x(0) into buffer 0
  if (tid < M && tid < nvalid) {
    hbuf[0][tid][130] = (_Float16)1.0f;
    hbuf[1][tid][130] = (_Float16)1.0f;
    *(unsigned int*)&hbuf[0][tid][128] = xb[tid][0];
  }
  __syncthreads();

  float cr[2][4] = {{0.f,0.f,0.f,0.f},{0.f,0.f,0.f,0.f}};

  for (int t = 0; t < T; ++t) {
    const int p = t & 1, qn = p ^ 1;
    // early x(t+1) write into buffer qn (disjoint from this step's reads of buffer p)
    if (lane < 4) {
      int m = (w << 2) | lane;
      unsigned int xv = (t+1 < T) ? xb[m][t+1] : 0u;
      *(unsigned int*)&hbuf[qn][m][128] = xv;
    }
    half8 A[5];
    #pragma unroll
    for (int kt = 0; kt < 5; ++kt)
      A[kt] = *(const half8*)&hbuf[p][lo][kt*32 + quad*8];

    f32x4 G[2][4];
    #pragma unroll
    for (int cgi = 0; cgi < 2; ++cgi)
      #pragma unroll
      for (int q = 0; q < 4; ++q)
        G[cgi][q] = (f32x4){0.f, 0.f, 0.f, 0.f};
    #pragma unroll
    for (int kt = 0; kt < 5; ++kt)      // 8 independent acc chains interleaved
      #pragma unroll
      for (int cgi = 0; cgi < 2; ++cgi)
        #pragma unroll
        for (int q = 0; q < 4; ++q)
          G[cgi][q] = __builtin_amdgcn_mfma_f32_16x16x32_f16(A[kt], Bf[q][cgi][kt], G[cgi][q], 0, 0, 0);

    #pragma unroll
    for (int cgi = 0; cgi < 2; ++cgi) {
      const int col = (2*w + cgi)*16 + lo;
      #pragma unroll
      for (int r = 0; r < 4; ++r) {
        float si = sigm(scrub(G[cgi][0][r]));
        float sf = sigm(scrub(G[cgi][1][r]));
        float tg = tanhx(scrub(G[cgi][2][r]));
        float so = sigm(scrub(G[cgi][3][r]));
        float c  = sf*cr[cgi][r] + si*tg;
        cr[cgi][r] = c;
        hbuf[qn][quad*4 + r][col] = (_Float16)(so*tanhx(c));
      }
    }
    __syncthreads();
    // ---- ballot-cooperative watcher copies (read buffer qn; safe until step t+2)
    #pragma unroll
    for (int s = 0; s < 2; ++s) {
      unsigned long long mask = __ballot(myt[s] == t);
      while (mask) {
        int src = __ffsll((unsigned long long)mask) - 1;
        mask &= mask - 1;
        int m   = __shfl(mym[s], src);
        int off = __shfl(myo[s], src);
        unsigned int pk = *(const unsigned int*)&hbuf[qn][m][2*lane];
        float2 v;
        v.x = (float)__builtin_bit_cast(_Float16, (unsigned short)(pk & 0xFFFFu));
        v.y = (float)__builtin_bit_cast(_Float16, (unsigned short)(pk >> 16));
        *(float2*)(ws + off + 2*lane) = v;
      }
    }
  }
}

__global__ void dists(const float* __restrict__ ws, void* __restrict__ outv) {
  const int fbf = ((const int*)(ws + WS_FLAGS))[0];
  const int gtid = blockIdx.x*256 + threadIdx.x;
  const int widx = gtid >> 6, lane = gtid & 63;
  const float *pa, *pb;
  if (widx < 220)       { pa = ws + WS_TEMB + (size_t)widx*H;        pb = ws + WS_AEMB + (size_t)widx*H; }
  else if (widx < 440)  { int b = widx-220;  pa = ws + WS_TEMB + (size_t)b*H; pb = ws + WS_AEMB + (BB*H) + (size_t)b*H; }
  else if (widx < 2640) { int k = widx-440;  pa = ws + WS_TA + (size_t)k*H;   pb = ws + WS_AN + (size_t)k*H; }
  else                  { int k = widx-2640; pa = ws + WS_TF + (size_t)k*H;   pb = ws + WS_FA + (size_t)k*H; }
  float d0 = pa[lane]    - pb[lane];
  float d1 = pa[lane+64] - pb[lane+64];
  float s  = scrub(d0*d0 + d1*d1);
  #pragma unroll
  for (int off = 32; off > 0; off >>= 1) s += __shfl_down(s, off, 64);
  if (lane == 0) {
    float r = __expf(-sqrtf(s));
    if (fbf) ((unsigned short*)outv)[widx] = f2bf(r);
    else     ((float*)outv)[widx] = r;
  }
}

extern "C" void kernel_launch(void* const* d_in, const int* in_sizes, int n_in,
                              void* d_out, int out_size, void* d_ws, size_t ws_size,
                              hipStream_t stream) {
  float* ws = (float*)d_ws;
  hipLaunchKernelGGL(lstm_scan, dim3(NBLK, 3), dim3(256), 0, stream,
                     d_in[0], d_in[1], d_in[2], d_in[3],
                     d_in[4], d_in[5], d_in[6],
                     d_in[7], d_in[8], d_in[9],
                     d_in[10], d_in[11], d_in[12], d_in[13], ws);
  hipLaunchKernelGGL(dists, dim3(4840*64/256), dim3(256), 0, stream, ws, d_out);
}

// Round 4
// 554.758 us; speedup vs baseline: 1.2802x; 1.2802x over previous
//
#include <hip/hip_runtime.h>

#define H    128
#define T    512
#define DX   4
#define BB   220
#define SAMP 10
#define NS   (BB*SAMP)
#define M    16       // sequences per block
#define HSTR 168      // hbuf row stride in halves (336 B, 16B-aligned)
#define NBLK 14       // ceil(220/16)

typedef _Float16 half8 __attribute__((ext_vector_type(8)));
typedef float    f32x4 __attribute__((ext_vector_type(4)));

// workspace layout (fp32 elements)
#define WS_TEMB 0
#define WS_AEMB (WS_TEMB + BB*H)
#define WS_FEMB (WS_AEMB + BB*H)
#define WS_TA   (WS_FEMB + BB*H)
#define WS_TF   (WS_TA + NS*H)
#define WS_AN   (WS_TF + NS*H)
#define WS_FA   (WS_AN + NS*H)
#define WS_FLAGS (WS_FA + NS*H)   // 2 ints: [0]=floats-are-bf16, [1]=ints-are-int64

#define LOG2E  1.442695041f
#define LOG2E2 2.885390082f

__device__ static inline float bf2f(unsigned short u) {
  unsigned int i = ((unsigned int)u) << 16;
  return __builtin_bit_cast(float, i);
}
__device__ static inline unsigned short f2bf(float f) {
  unsigned int i = __builtin_bit_cast(unsigned int, f);
  i += 0x7fffu + ((i >> 16) & 1u);
  return (unsigned short)(i >> 16);
}
__device__ static inline float loadF(const void* p, size_t i, int isbf) {
  return isbf ? bf2f(((const unsigned short*)p)[i]) : ((const float*)p)[i];
}
__device__ static inline int loadI(const void* p, int i, int is64) {
  return is64 ? (int)((const unsigned int*)p)[2*(size_t)i] : ((const int*)p)[i];
}
__device__ static inline float frcp(float x) { return __builtin_amdgcn_rcpf(x); }
__device__ static inline float ex2(float x)  { return __builtin_amdgcn_exp2f(x); }
// inputs pre-scaled by log2e (sigm) / 2*log2e (tanh): one exp2 + add + rcp each
__device__ static inline float sigmY(float y)  { return frcp(1.f + ex2(-y)); }  // y = x*log2e
__device__ static inline float tanhY(float y)  { return 1.f - 2.f*frcp(1.f + ex2(y)); } // y = 2x*log2e
__device__ static inline float scrub(float x) { return (x == x) ? x : 0.f; }
__device__ static inline int clampT(int v) { v = v - 1; if (v < 0) v = 0; if (v > T-1) v = T-1; return v; }

__global__ __launch_bounds__(512, 2) void lstm_scan(
    const void* __restrict__ x0_, const void* __restrict__ len0,
    const void* __restrict__ sub_ta, const void* __restrict__ sub_tf,
    const void* __restrict__ x1_, const void* __restrict__ len1,
    const void* __restrict__ sub_an,
    const void* __restrict__ x2_, const void* __restrict__ len2,
    const void* __restrict__ sub_fa,
    const void* __restrict__ Wih, const void* __restrict__ Whh,
    const void* __restrict__ bih, const void* __restrict__ bhh,
    float* __restrict__ ws)
{
  const int e      = blockIdx.y;
  const int s0     = blockIdx.x * M;
  const int nvalid = (BB - s0) < M ? (BB - s0) : M;
  const int tid    = threadIdx.x;
  const int lane   = tid & 63;
  const int w      = tid >> 6;     // wave 0..7, owns col-group w (h-cols [16w,16w+16))
  const int lo     = lane & 15;
  const int quad   = lane >> 4;

  // ---- in-block dtype detection (uniform scalar loop; block (0,0) publishes for dists)
  int fbf, f64;
  {
    const unsigned int* wp = (const unsigned int*)Whh;
    int cnt = 0;
    for (int i = 0; i < 64; ++i) {
      unsigned int lo16 = wp[i] & 0xFFFFu;
      int ex = (int)((lo16 >> 7) & 0xFFu);
      cnt += (ex >= 100 && ex <= 130);
    }
    fbf = (cnt >= 40);
    const unsigned int* l = (const unsigned int*)len0;
    f64 = ((l[1] | l[3] | l[5] | l[7]) == 0u);
    if (blockIdx.x == 0 && blockIdx.y == 0 && tid == 0) {
      int* fo = (int*)(ws + WS_FLAGS); fo[0] = fbf; fo[1] = f64;
    }
  }

  const void* xin  = (e==0) ? x0_ : (e==1 ? x1_ : x2_);
  const void* lenp = (e==0) ? len0 : (e==1 ? len1 : len2);

  __shared__ __align__(16) _Float16 hbuf[2][M][HSTR];  // h'(t) double-buffered, K=160 used
  __shared__ unsigned int xb[M][T+1];                  // f16x2 packed x, stride 513

  {
    unsigned int* hz = (unsigned int*)hbuf;
    for (int i = tid; i < M*HSTR; i += 512) hz[i] = 0u;
  }
  // ---- stage x[:, :, 0:2] to LDS as f16 pairs
  for (int i = tid; i < M*T; i += 512) {
    int m = i >> 9, t = i & (T-1);
    unsigned int v = 0u;
    if (m < nvalid) {
      size_t base = ((size_t)(s0+m)*T + t) * DX;
      _Float16 ha = (_Float16)loadF(xin, base + 0, fbf);
      _Float16 hb = (_Float16)loadF(xin, base + 1, fbf);
      v = (unsigned int)__builtin_bit_cast(unsigned short, ha)
        | ((unsigned int)__builtin_bit_cast(unsigned short, hb) << 16);
    }
    xb[m][t] = v;
  }
  // ---- weight B-fragments: W' = [W_hh | W_ih | b_ih+b_hh | 0] as K=160
  // pre-scaled: gates i,f,o by log2e; gate g by 2*log2e (exp2-native activations)
  half8 Bf[4][5];
  #pragma unroll
  for (int q = 0; q < 4; ++q) {
    const float sc = (q == 2) ? LOG2E2 : LOG2E;
    const int g = q*128 + w*16 + lo;
    #pragma unroll
    for (int kt = 0; kt < 5; ++kt) {
      #pragma unroll
      for (int j = 0; j < 8; ++j) {
        const int k = kt*32 + quad*8 + j;
        float v;
        if      (k < 128)  v = loadF(Whh, (size_t)g*H + k, fbf);
        else if (k == 128) v = loadF(Wih, (size_t)g*2 + 0, fbf);
        else if (k == 129) v = loadF(Wih, (size_t)g*2 + 1, fbf);
        else if (k == 130) v = loadF(bih, g, fbf) + loadF(bhh, g, fbf);
        else               v = 0.f;
        Bf[q][kt][j] = (_Float16)(sc * v);
      }
    }
  }
  // ---- per-thread watcher slot (single: max 336 < 512 threads)
  int myt = -1, mym = 0, myo = 0;
  if (e == 0) {
    if (tid < nvalid*21) {
      int m = tid / 21, j = tid - m*21, sg = s0 + m;
      mym = m;
      if (j == 0)       { myt = clampT(loadI(lenp, sg, f64));            myo = WS_TEMB + sg*H; }
      else if (j <= 10) { int k = sg*10 + (j-1);  myt = clampT(loadI(sub_ta, k, f64)); myo = WS_TA + k*H; }
      else              { int k = sg*10 + (j-11); myt = clampT(loadI(sub_tf, k, f64)); myo = WS_TF + k*H; }
    }
  } else {
    if (tid < nvalid*11) {
      int m = tid / 11, j = tid - m*11, sg = s0 + m;
      mym = m;
      if (j == 0) { myt = clampT(loadI(lenp, sg, f64)); myo = (e==1 ? WS_AEMB : WS_FEMB) + sg*H; }
      else {
        int k = sg*10 + (j-1);
        if (e == 1) { myt = clampT(loadI(sub_an, k, f64)); myo = WS_AN + k*H; }
        else        { myt = clampT(loadI(sub_fa, k, f64)); myo = WS_FA + k*H; }
      }
    }
  }
  __syncthreads();
  if (tid < M && tid < nvalid) {
    hbuf[0][tid][130] = (_Float16)1.0f;
    hbuf[1][tid][130] = (_Float16)1.0f;
    *(unsigned int*)&hbuf[0][tid][128] = xb[tid][0];
  }
  __syncthreads();

  float cr[4] = {0.f, 0.f, 0.f, 0.f};
  const int col = w*16 + lo;

  for (int t = 0; t < T; ++t) {
    const int p = t & 1, qn = p ^ 1;
    // early x(t+1) write into buffer qn (disjoint from this step's reads of p)
    if (lane < 2) {
      int m = (w << 1) | lane;
      unsigned int xv = (t+1 < T) ? xb[m][t+1] : 0u;
      *(unsigned int*)&hbuf[qn][m][128] = xv;
    }
    half8 A[5];
    #pragma unroll
    for (int kt = 0; kt < 5; ++kt)
      A[kt] = *(const half8*)&hbuf[p][lo][kt*32 + quad*8];

    f32x4 G[4];
    #pragma unroll
    for (int q = 0; q < 4; ++q) G[q] = (f32x4){0.f, 0.f, 0.f, 0.f};
    #pragma unroll
    for (int kt = 0; kt < 5; ++kt)      // 4 independent acc chains interleaved
      #pragma unroll
      for (int q = 0; q < 4; ++q)
        G[q] = __builtin_amdgcn_mfma_f32_16x16x32_f16(A[kt], Bf[q][kt], G[q], 0, 0, 0);

    #pragma unroll
    for (int r = 0; r < 4; ++r) {
      float si = sigmY(G[0][r]);
      float sf = sigmY(G[1][r]);
      float tg = tanhY(G[2][r]);
      float so = sigmY(G[3][r]);
      float c  = sf*cr[r] + si*tg;
      cr[r] = c;
      hbuf[qn][quad*4 + r][col] = (_Float16)(so * tanhY(c * LOG2E2));
    }
    __syncthreads();
    // ---- ballot-cooperative watcher copies (read buffer qn; safe until step t+2)
    unsigned long long mask = __ballot(myt == t);
    while (mask) {
      int src = __ffsll((unsigned long long)mask) - 1;
      mask &= mask - 1;
      int m   = __shfl(mym, src);
      int off = __shfl(myo, src);
      unsigned int pk = *(const unsigned int*)&hbuf[qn][m][2*lane];
      float2 v;
      v.x = (float)__builtin_bit_cast(_Float16, (unsigned short)(pk & 0xFFFFu));
      v.y = (float)__builtin_bit_cast(_Float16, (unsigned short)(pk >> 16));
      *(float2*)(ws + off + 2*lane) = v;
    }
  }
}

__global__ void dists(const float* __restrict__ ws, void* __restrict__ outv) {
  const int fbf = ((const int*)(ws + WS_FLAGS))[0];
  const int gtid = blockIdx.x*256 + threadIdx.x;
  const int widx = gtid >> 6, lane = gtid & 63;
  const float *pa, *pb;
  if (widx < 220)       { pa = ws + WS_TEMB + (size_t)widx*H;        pb = ws + WS_AEMB + (size_t)widx*H; }
  else if (widx < 440)  { int b = widx-220;  pa = ws + WS_TEMB + (size_t)b*H; pb = ws + WS_FEMB + (size_t)b*H; }
  else if (widx < 2640) { int k = widx-440;  pa = ws + WS_TA + (size_t)k*H;   pb = ws + WS_AN + (size_t)k*H; }
  else                  { int k = widx-2640; pa = ws + WS_TF + (size_t)k*H;   pb = ws + WS_FA + (size_t)k*H; }
  float d0 = pa[lane]    - pb[lane];
  float d1 = pa[lane+64] - pb[lane+64];
  float s  = scrub(d0*d0 + d1*d1);
  #pragma unroll
  for (int off = 32; off > 0; off >>= 1) s += __shfl_down(s, off, 64);
  if (lane == 0) {
    float r = __expf(-sqrtf(s));
    if (fbf) ((unsigned short*)outv)[widx] = f2bf(r);
    else     ((float*)outv)[widx] = r;
  }
}

extern "C" void kernel_launch(void* const* d_in, const int* in_sizes, int n_in,
                              void* d_out, int out_size, void* d_ws, size_t ws_size,
                              hipStream_t stream) {
  float* ws = (float*)d_ws;
  hipLaunchKernelGGL(lstm_scan, dim3(NBLK, 3), dim3(512), 0, stream,
                     d_in[0], d_in[1], d_in[2], d_in[3],
                     d_in[4], d_in[5], d_in[6],
                     d_in[7], d_in[8], d_in[9],
                     d_in[10], d_in[11], d_in[12], d_in[13], ws);
  hipLaunchKernelGGL(dists, dim3(4840*64/256), dim3(256), 0, stream, ws, d_out);
}

// Round 5
// 484.656 us; speedup vs baseline: 1.4653x; 1.1446x over previous
//
#include <hip/hip_runtime.h>

#define H    128
#define T    512
#define DX   4
#define BB   220
#define SAMP 10
#define NS   (BB*SAMP)
#define M    4        // sequences per block (220 = 55*4, no tail)
#define HSTR 168      // hbuf row stride in halves (336 B)
#define NBLK 55       // 220/4

typedef _Float16 half8 __attribute__((ext_vector_type(8)));
typedef float    f32x4 __attribute__((ext_vector_type(4)));

// workspace layout (fp32 elements)
#define WS_TEMB 0
#define WS_AEMB (WS_TEMB + BB*H)
#define WS_FEMB (WS_AEMB + BB*H)
#define WS_TA   (WS_FEMB + BB*H)
#define WS_TF   (WS_TA + NS*H)
#define WS_AN   (WS_TF + NS*H)
#define WS_FA   (WS_AN + NS*H)
#define WS_FLAGS (WS_FA + NS*H)   // 2 ints: [0]=floats-are-bf16, [1]=ints-are-int64

#define LOG2E  1.442695041f
#define LOG2E2 2.885390082f

__device__ static inline float bf2f(unsigned short u) {
  unsigned int i = ((unsigned int)u) << 16;
  return __builtin_bit_cast(float, i);
}
__device__ static inline unsigned short f2bf(float f) {
  unsigned int i = __builtin_bit_cast(unsigned int, f);
  i += 0x7fffu + ((i >> 16) & 1u);
  return (unsigned short)(i >> 16);
}
__device__ static inline float loadF(const void* p, size_t i, int isbf) {
  return isbf ? bf2f(((const unsigned short*)p)[i]) : ((const float*)p)[i];
}
__device__ static inline int loadI(const void* p, int i, int is64) {
  return is64 ? (int)((const unsigned int*)p)[2*(size_t)i] : ((const int*)p)[i];
}
__device__ static inline float frcp(float x) { return __builtin_amdgcn_rcpf(x); }
__device__ static inline float ex2(float x)  { return __builtin_amdgcn_exp2f(x); }
// inputs pre-scaled by log2e (sigm) / 2*log2e (tanh): one exp2 + add + rcp each
__device__ static inline float sigmY(float y)  { return frcp(1.f + ex2(-y)); }
__device__ static inline float tanhY(float y)  { return 1.f - 2.f*frcp(1.f + ex2(y)); }
__device__ static inline float scrub(float x) { return (x == x) ? x : 0.f; }
__device__ static inline int clampT(int v) { v = v - 1; if (v < 0) v = 0; if (v > T-1) v = T-1; return v; }

__global__ __launch_bounds__(512, 2) void lstm_scan(
    const void* __restrict__ x0_, const void* __restrict__ len0,
    const void* __restrict__ sub_ta, const void* __restrict__ sub_tf,
    const void* __restrict__ x1_, const void* __restrict__ len1,
    const void* __restrict__ sub_an,
    const void* __restrict__ x2_, const void* __restrict__ len2,
    const void* __restrict__ sub_fa,
    const void* __restrict__ Wih, const void* __restrict__ Whh,
    const void* __restrict__ bih, const void* __restrict__ bhh,
    float* __restrict__ ws)
{
  const int e      = blockIdx.y;
  const int s0     = blockIdx.x * M;
  const int tid    = threadIdx.x;
  const int lane   = tid & 63;
  const int w      = tid >> 6;     // wave 0..7, owns h-cols [16w,16w+16)
  const int lo     = lane & 15;
  const int quad   = lane >> 4;    // also: my seq-row for elementwise

  // ---- in-block dtype detection (uniform scalar loop; block (0,0) publishes for dists)
  int fbf, f64;
  {
    const unsigned int* wp = (const unsigned int*)Whh;
    int cnt = 0;
    for (int i = 0; i < 64; ++i) {
      unsigned int lo16 = wp[i] & 0xFFFFu;
      int ex = (int)((lo16 >> 7) & 0xFFu);
      cnt += (ex >= 100 && ex <= 130);
    }
    fbf = (cnt >= 40);
    const unsigned int* l = (const unsigned int*)len0;
    f64 = ((l[1] | l[3] | l[5] | l[7]) == 0u);
    if (blockIdx.x == 0 && blockIdx.y == 0 && tid == 0) {
      int* fo = (int*)(ws + WS_FLAGS); fo[0] = fbf; fo[1] = f64;
    }
  }

  const void* xin  = (e==0) ? x0_ : (e==1 ? x1_ : x2_);
  const void* lenp = (e==0) ? len0 : (e==1 ? len1 : len2);

  __shared__ __align__(16) _Float16 hbuf[2][M][HSTR];   // h'(t) double-buffered, K=160
  __shared__ unsigned int xb[M][T+1];                   // f16x2 packed x, stride 513
  __shared__ __align__(16) float gbuf[8][16][20];       // per-wave gate bounce, 80B rows

  {
    unsigned int* hz = (unsigned int*)hbuf;
    for (int i = tid; i < M*HSTR; i += 512) hz[i] = 0u;  // 2*M*HSTR halves
  }
  // ---- stage x[:, :, 0:2] to LDS as f16 pairs
  for (int i = tid; i < M*T; i += 512) {
    int m = i >> 9, t = i & (T-1);
    size_t base = ((size_t)(s0+m)*T + t) * DX;
    _Float16 ha = (_Float16)loadF(xin, base + 0, fbf);
    _Float16 hb = (_Float16)loadF(xin, base + 1, fbf);
    xb[m][t] = (unsigned int)__builtin_bit_cast(unsigned short, ha)
             | ((unsigned int)__builtin_bit_cast(unsigned short, hb) << 16);
  }
  // ---- weight B-fragments: W' = [W_hh | W_ih | b_ih+b_hh | 0] as K=160
  // pre-scaled: gates i,f,o by log2e; gate g by 2*log2e (exp2-native activations)
  half8 Bf[4][5];
  #pragma unroll
  for (int q = 0; q < 4; ++q) {
    const float sc = (q == 2) ? LOG2E2 : LOG2E;
    const int g = q*128 + w*16 + lo;
    #pragma unroll
    for (int kt = 0; kt < 5; ++kt) {
      #pragma unroll
      for (int j = 0; j < 8; ++j) {
        const int k = kt*32 + quad*8 + j;
        float v;
        if      (k < 128)  v = loadF(Whh, (size_t)g*H + k, fbf);
        else if (k == 128) v = loadF(Wih, (size_t)g*2 + 0, fbf);
        else if (k == 129) v = loadF(Wih, (size_t)g*2 + 1, fbf);
        else if (k == 130) v = loadF(bih, g, fbf) + loadF(bhh, g, fbf);
        else               v = 0.f;
        Bf[q][kt][j] = (_Float16)(sc * v);
      }
    }
  }
  // ---- per-thread watcher slot (max M*21 = 84 < 512)
  int myt = -1, mym = 0, myo = 0;
  if (e == 0) {
    if (tid < M*21) {
      int m = tid / 21, j = tid - m*21, sg = s0 + m;
      mym = m;
      if (j == 0)       { myt = clampT(loadI(lenp, sg, f64));            myo = WS_TEMB + sg*H; }
      else if (j <= 10) { int k = sg*10 + (j-1);  myt = clampT(loadI(sub_ta, k, f64)); myo = WS_TA + k*H; }
      else              { int k = sg*10 + (j-11); myt = clampT(loadI(sub_tf, k, f64)); myo = WS_TF + k*H; }
    }
  } else {
    if (tid < M*11) {
      int m = tid / 11, j = tid - m*11, sg = s0 + m;
      mym = m;
      if (j == 0) { myt = clampT(loadI(lenp, sg, f64)); myo = (e==1 ? WS_AEMB : WS_FEMB) + sg*H; }
      else {
        int k = sg*10 + (j-1);
        if (e == 1) { myt = clampT(loadI(sub_an, k, f64)); myo = WS_AN + k*H; }
        else        { myt = clampT(loadI(sub_fa, k, f64)); myo = WS_FA + k*H; }
      }
    }
  }
  __syncthreads();
  if (tid < M) {
    hbuf[0][tid][130] = (_Float16)1.0f;      // constant-1 column (never overwritten)
    hbuf[1][tid][130] = (_Float16)1.0f;
    *(unsigned int*)&hbuf[0][tid][128] = xb[tid][0];
  }
  __syncthreads();

  float cc = 0.f;                 // c-state for my cell (seq=quad, col=w*16+lo)
  const int col = w*16 + lo;

  for (int t = 0; t < T; ++t) {
    const int p = t & 1, qn = p ^ 1;
    // early x(t+1) into buffer qn (wave 0 only; disjoint from this step's reads of p)
    if (w == 0) {
      if (lane < M) {
        unsigned int xv = (t+1 < T) ? xb[lane][t+1] : 0u;
        *(unsigned int*)&hbuf[qn][lane][128] = xv;
      }
    }
    // A-fragments: 4 real rows, lanes lo>=4 broadcast-duplicate (free in banks)
    half8 A[5];
    #pragma unroll
    for (int kt = 0; kt < 5; ++kt)
      A[kt] = *(const half8*)&hbuf[p][lo & 3][kt*32 + quad*8];

    f32x4 G[4];
    #pragma unroll
    for (int q = 0; q < 4; ++q) G[q] = (f32x4){0.f, 0.f, 0.f, 0.f};
    #pragma unroll
    for (int kt = 0; kt < 5; ++kt)
      #pragma unroll
      for (int q = 0; q < 4; ++q)
        G[q] = __builtin_amdgcn_mfma_f32_16x16x32_f16(A[kt], Bf[q][kt], G[q], 0, 0, 0);

    // ---- per-wave redistribution: quad0 holds all real rows (seqs 0..3)
    if (quad == 0) {
      #pragma unroll
      for (int q = 0; q < 4; ++q)
        *(f32x4*)&gbuf[w][lo][q*4] = G[q];    // [q][r] order, 16B-aligned
    }
    // same-wave LDS ordering: reads below see the writes (lgkmcnt, no barrier)
    float R0 = gbuf[w][lo][0*4 + quad];
    float R1 = gbuf[w][lo][1*4 + quad];
    float R2 = gbuf[w][lo][2*4 + quad];
    float R3 = gbuf[w][lo][3*4 + quad];

    float si = sigmY(R0);
    float sf = sigmY(R1);
    float tg = tanhY(R2);
    float so = sigmY(R3);
    cc = sf*cc + si*tg;
    hbuf[qn][quad][col] = (_Float16)(so * tanhY(cc * LOG2E2));
    __syncthreads();
    // ---- ballot-cooperative watcher copies (read buffer qn; safe until step t+2)
    unsigned long long mask = __ballot(myt == t);
    while (mask) {
      int src = __ffsll((unsigned long long)mask) - 1;
      mask &= mask - 1;
      int m   = __shfl(mym, src);
      int off = __shfl(myo, src);
      unsigned int pk = *(const unsigned int*)&hbuf[qn][m][2*lane];
      float2 v;
      v.x = (float)__builtin_bit_cast(_Float16, (unsigned short)(pk & 0xFFFFu));
      v.y = (float)__builtin_bit_cast(_Float16, (unsigned short)(pk >> 16));
      *(float2*)(ws + off + 2*lane) = v;
    }
  }
}

__global__ void dists(const float* __restrict__ ws, void* __restrict__ outv) {
  const int fbf = ((const int*)(ws + WS_FLAGS))[0];
  const int gtid = blockIdx.x*256 + threadIdx.x;
  const int widx = gtid >> 6, lane = gtid & 63;
  const float *pa, *pb;
  if (widx < 220)       { pa = ws + WS_TEMB + (size_t)widx*H;        pb = ws + WS_AEMB + (size_t)widx*H; }
  else if (widx < 440)  { int b = widx-220;  pa = ws + WS_TEMB + (size_t)b*H; pb = ws + WS_FEMB + (size_t)b*H; }
  else if (widx < 2640) { int k = widx-440;  pa = ws + WS_TA + (size_t)k*H;   pb = ws + WS_AN + (size_t)k*H; }
  else                  { int k = widx-2640; pa = ws + WS_TF + (size_t)k*H;   pb = ws + WS_FA + (size_t)k*H; }
  float d0 = pa[lane]    - pb[lane];
  float d1 = pa[lane+64] - pb[lane+64];
  float s  = scrub(d0*d0 + d1*d1);
  #pragma unroll
  for (int off = 32; off > 0; off >>= 1) s += __shfl_down(s, off, 64);
  if (lane == 0) {
    float r = __expf(-sqrtf(s));
    if (fbf) ((unsigned short*)outv)[widx] = f2bf(r);
    else     ((float*)outv)[widx] = r;
  }
}

extern "C" void kernel_launch(void* const* d_in, const int* in_sizes, int n_in,
                              void* d_out, int out_size, void* d_ws, size_t ws_size,
                              hipStream_t stream) {
  float* ws = (float*)d_ws;
  hipLaunchKernelGGL(lstm_scan, dim3(NBLK, 3), dim3(512), 0, stream,
                     d_in[0], d_in[1], d_in[2], d_in[3],
                     d_in[4], d_in[5], d_in[6],
                     d_in[7], d_in[8], d_in[9],
                     d_in[10], d_in[11], d_in[12], d_in[13], ws);
  hipLaunchKernelGGL(dists, dim3(4840*64/256), dim3(256), 0, stream, ws, d_out);
}

// Round 6
// 458.428 us; speedup vs baseline: 1.5492x; 1.0572x over previous
//
#include <hip/hip_runtime.h>

#define H    128
#define T    512
#define DX   4
#define BB   220
#define SAMP 10
#define NS   (BB*SAMP)
#define M    4        // sequences per block (220 = 55*4, no tail)
#define NBLK 55       // 220/4

typedef _Float16 half8 __attribute__((ext_vector_type(8)));
typedef float    f32x4 __attribute__((ext_vector_type(4)));

// workspace layout (fp32 elements)
#define WS_TEMB 0
#define WS_AEMB (WS_TEMB + BB*H)
#define WS_FEMB (WS_AEMB + BB*H)
#define WS_TA   (WS_FEMB + BB*H)
#define WS_TF   (WS_TA + NS*H)
#define WS_AN   (WS_TF + NS*H)
#define WS_FA   (WS_AN + NS*H)
#define WS_FLAGS (WS_FA + NS*H)   // 2 ints: [0]=floats-are-bf16, [1]=ints-are-int64

#define LOG2E  1.442695041f
#define LOG2E2 2.885390082f

__device__ static inline float bf2f(unsigned short u) {
  unsigned int i = ((unsigned int)u) << 16;
  return __builtin_bit_cast(float, i);
}
__device__ static inline unsigned short f2bf(float f) {
  unsigned int i = __builtin_bit_cast(unsigned int, f);
  i += 0x7fffu + ((i >> 16) & 1u);
  return (unsigned short)(i >> 16);
}
__device__ static inline float loadF(const void* p, size_t i, int isbf) {
  return isbf ? bf2f(((const unsigned short*)p)[i]) : ((const float*)p)[i];
}
__device__ static inline int loadI(const void* p, int i, int is64) {
  return is64 ? (int)((const unsigned int*)p)[2*(size_t)i] : ((const int*)p)[i];
}
__device__ static inline float frcp(float x) { return __builtin_amdgcn_rcpf(x); }
__device__ static inline float ex2(float x)  { return __builtin_amdgcn_exp2f(x); }
// args pre-scaled by log2e (sigm) / 2*log2e (tanh)
__device__ static inline float sigmY(float y)  { return frcp(1.f + ex2(-y)); }
__device__ static inline float tanhY(float y)  { return 1.f - 2.f*frcp(1.f + ex2(y)); }
__device__ static inline float scrub(float x) { return (x == x) ? x : 0.f; }
__device__ static inline int clampT(int v) { v = v - 1; if (v < 0) v = 0; if (v > T-1) v = T-1; return v; }

__global__ __launch_bounds__(512, 2) void lstm_scan(
    const void* __restrict__ x0_, const void* __restrict__ len0,
    const void* __restrict__ sub_ta, const void* __restrict__ sub_tf,
    const void* __restrict__ x1_, const void* __restrict__ len1,
    const void* __restrict__ sub_an,
    const void* __restrict__ x2_, const void* __restrict__ len2,
    const void* __restrict__ sub_fa,
    const void* __restrict__ Wih, const void* __restrict__ Whh,
    const void* __restrict__ bih, const void* __restrict__ bhh,
    float* __restrict__ ws)
{
  const int e      = blockIdx.y;
  const int s0     = blockIdx.x * M;
  const int tid    = threadIdx.x;
  const int lane   = tid & 63;
  const int w      = tid >> 6;     // wave 0..7, owns h-cols [16w,16w+16)
  const int lo     = lane & 15;
  const int quad   = lane >> 4;    // elementwise: my seq

  // ---- in-block dtype detection (uniform scalar loop; block (0,0) publishes for dists)
  int fbf, f64;
  {
    const unsigned int* wp = (const unsigned int*)Whh;
    int cnt = 0;
    for (int i = 0; i < 64; ++i) {
      unsigned int lo16 = wp[i] & 0xFFFFu;
      int ex = (int)((lo16 >> 7) & 0xFFu);
      cnt += (ex >= 100 && ex <= 130);
    }
    fbf = (cnt >= 40);
    const unsigned int* l = (const unsigned int*)len0;
    f64 = ((l[1] | l[3] | l[5] | l[7]) == 0u);
    if (blockIdx.x == 0 && blockIdx.y == 0 && tid == 0) {
      int* fo = (int*)(ws + WS_FLAGS); fo[0] = fbf; fo[1] = f64;
    }
  }

  const void* xin  = (e==0) ? x0_ : (e==1 ? x1_ : x2_);
  const void* lenp = (e==0) ? len0 : (e==1 ? len1 : len2);

  // h'(t) in MFMA-fragment-major order: [buf][ktile][chunk=quad'*4+seq][8 halves]
  // element h[s][c] lives at [c>>5][((c>>3)&3)*4+s][c&7]
  __shared__ __align__(16) _Float16 afr[2][4][16][8];
  __shared__ __align__(16) float2 xbf[M][T+2];          // x pairs, stride T+2 (bank-spread)
  __shared__ __align__(16) float gbuf[8][16][20];       // per-wave gate bounce, 80B rows

  if (tid < 512) ((unsigned int*)afr)[tid] = 0u;        // zero both h buffers (512 dw)
  // ---- stage x[:, :, 0:2] to LDS as f32 pairs
  for (int i = tid; i < M*T; i += 512) {
    int m = i >> 9, t = i & (T-1);
    size_t base = ((size_t)(s0+m)*T + t) * DX;
    xbf[m][t] = make_float2(loadF(xin, base + 0, fbf), loadF(xin, base + 1, fbf));
  }
  // ---- weight B-fragments: W_hh only, K=128; pre-scaled (i,f,o: log2e; g: 2*log2e)
  half8 Bf[4][4];
  const int col = w*16 + lo;
  #pragma unroll
  for (int q = 0; q < 4; ++q) {
    const float sc = (q == 2) ? LOG2E2 : LOG2E;
    const int g = q*128 + col;
    #pragma unroll
    for (int kt = 0; kt < 4; ++kt) {
      #pragma unroll
      for (int j = 0; j < 8; ++j) {
        const int k = kt*32 + quad*8 + j;
        Bf[q][kt][j] = (_Float16)(sc * loadF(Whh, (size_t)g*H + k, fbf));
      }
    }
  }
  // ---- per-lane x-weights and bias (for my elementwise cell: seq=quad, col)
  float wx0[4], wx1[4], bb[4];
  #pragma unroll
  for (int q = 0; q < 4; ++q) {
    const float sc = (q == 2) ? LOG2E2 : LOG2E;
    const int g = q*128 + col;
    wx0[q] = sc * loadF(Wih, (size_t)g*2 + 0, fbf);
    wx1[q] = sc * loadF(Wih, (size_t)g*2 + 1, fbf);
    bb[q]  = sc * (loadF(bih, g, fbf) + loadF(bhh, g, fbf));
  }
  // ---- per-thread watcher slot (max M*21 = 84 < 512)
  int myt = -1, mym = 0, myo = 0;
  if (e == 0) {
    if (tid < M*21) {
      int m = tid / 21, j = tid - m*21, sg = s0 + m;
      mym = m;
      if (j == 0)       { myt = clampT(loadI(lenp, sg, f64));            myo = WS_TEMB + sg*H; }
      else if (j <= 10) { int k = sg*10 + (j-1);  myt = clampT(loadI(sub_ta, k, f64)); myo = WS_TA + k*H; }
      else              { int k = sg*10 + (j-11); myt = clampT(loadI(sub_tf, k, f64)); myo = WS_TF + k*H; }
    }
  } else {
    if (tid < M*11) {
      int m = tid / 11, j = tid - m*11, sg = s0 + m;
      mym = m;
      if (j == 0) { myt = clampT(loadI(lenp, sg, f64)); myo = (e==1 ? WS_AEMB : WS_FEMB) + sg*H; }
      else {
        int k = sg*10 + (j-1);
        if (e == 1) { myt = clampT(loadI(sub_an, k, f64)); myo = WS_AN + k*H; }
        else        { myt = clampT(loadI(sub_fa, k, f64)); myo = WS_FA + k*H; }
      }
    }
  }
  __syncthreads();

  float cc = 0.f;                 // c-state for my cell (seq=quad, col)
  const int rdchunk = quad*4 + (lo & 3);                    // A-frag read chunk
  const int wrkt    = w >> 1;                               // h-write ktile
  const int wrchunk = ((w & 1)*2 + (lo >> 3))*4 + quad;     // h-write chunk
  const int wrj     = lo & 7;                               // h-write j

  for (int t = 0; t < T; ++t) {
    const int p = t & 1, qn = p ^ 1;
    // A-fragments: conflict-free (16 contiguous 16B chunks, 4-lane broadcast)
    half8 A[4];
    #pragma unroll
    for (int kt = 0; kt < 4; ++kt)
      A[kt] = *(const half8*)&afr[p][kt][rdchunk][0];

    f32x4 G[4];
    #pragma unroll
    for (int q = 0; q < 4; ++q) G[q] = (f32x4){0.f, 0.f, 0.f, 0.f};
    #pragma unroll
    for (int kt = 0; kt < 4; ++kt)
      #pragma unroll
      for (int q = 0; q < 4; ++q)
        G[q] = __builtin_amdgcn_mfma_f32_16x16x32_f16(A[kt], Bf[q][kt], G[q], 0, 0, 0);

    // ---- per-wave redistribution: quad0 holds real rows (seqs 0..3)
    if (quad == 0) {
      #pragma unroll
      for (int q = 0; q < 4; ++q)
        *(f32x4*)&gbuf[w][lo][q*4] = G[q];
    }
    // same-wave LDS ordering: no barrier needed
    float2 xv = xbf[quad][t];
    float R[4];
    #pragma unroll
    for (int q = 0; q < 4; ++q) {
      float r = gbuf[w][lo][q*4 + quad];
      r += bb[q] + wx0[q]*xv.x + wx1[q]*xv.y;   // x + bias fold (was a K-tile)
      R[q] = r;
    }
    float si = sigmY(R[0]);
    float sf = sigmY(R[1]);
    float tg = tanhY(R[2]);
    float so = sigmY(R[3]);
    cc = sf*cc + si*tg;
    afr[qn][wrkt][wrchunk][wrj] = (_Float16)(so * tanhY(cc * LOG2E2));
    __syncthreads();
    // ---- ballot-cooperative watcher copies (read buffer qn; next step writes p)
    unsigned long long mask = __ballot(myt == t);
    while (mask) {
      int src = __ffsll((unsigned long long)mask) - 1;
      mask &= mask - 1;
      int m   = __shfl(mym, src);
      int off = __shfl(myo, src);
      int c0  = 2*lane;
      unsigned int pk = *(const unsigned int*)&afr[qn][c0>>5][((c0>>3)&3)*4 + m][c0&7];
      float2 v;
      v.x = (float)__builtin_bit_cast(_Float16, (unsigned short)(pk & 0xFFFFu));
      v.y = (float)__builtin_bit_cast(_Float16, (unsigned short)(pk >> 16));
      *(float2*)(ws + off + c0) = v;
    }
  }
}

__global__ void dists(const float* __restrict__ ws, void* __restrict__ outv) {
  const int fbf = ((const int*)(ws + WS_FLAGS))[0];
  const int gtid = blockIdx.x*256 + threadIdx.x;
  const int widx = gtid >> 6, lane = gtid & 63;
  const float *pa, *pb;
  if (widx < 220)       { pa = ws + WS_TEMB + (size_t)widx*H;        pb = ws + WS_AEMB + (size_t)widx*H; }
  else if (widx < 440)  { int b = widx-220;  pa = ws + WS_TEMB + (size_t)b*H; pb = ws + WS_FEMB + (size_t)b*H; }
  else if (widx < 2640) { int k = widx-440;  pa = ws + WS_TA + (size_t)k*H;   pb = ws + WS_AN + (size_t)k*H; }
  else                  { int k = widx-2640; pa = ws + WS_TF + (size_t)k*H;   pb = ws + WS_FA + (size_t)k*H; }
  float d0 = pa[lane]    - pb[lane];
  float d1 = pa[lane+64] - pb[lane+64];
  float s  = scrub(d0*d0 + d1*d1);
  #pragma unroll
  for (int off = 32; off > 0; off >>= 1) s += __shfl_down(s, off, 64);
  if (lane == 0) {
    float r = __expf(-sqrtf(s));
    if (fbf) ((unsigned short*)outv)[widx] = f2bf(r);
    else     ((float*)outv)[widx] = r;
  }
}

extern "C" void kernel_launch(void* const* d_in, const int* in_sizes, int n_in,
                              void* d_out, int out_size, void* d_ws, size_t ws_size,
                              hipStream_t stream) {
  float* ws = (float*)d_ws;
  hipLaunchKernelGGL(lstm_scan, dim3(NBLK, 3), dim3(512), 0, stream,
                     d_in[0], d_in[1], d_in[2], d_in[3],
                     d_in[4], d_in[5], d_in[6],
                     d_in[7], d_in[8], d_in[9],
                     d_in[10], d_in[11], d_in[12], d_in[13], ws);
  hipLaunchKernelGGL(dists, dim3(4840*64/256), dim3(256), 0, stream, ws, d_out);
}

// Round 7
// 390.075 us; speedup vs baseline: 1.8206x; 1.1752x over previous
//
#include <hip/hip_runtime.h>

#define H    128
#define T    512
#define DX   4
#define BB   220
#define SAMP 10
#define NS   (BB*SAMP)
#define M    4        // sequences per block (220 = 55*4, no tail)
#define NBLK 55       // 220/4
#define MAXSLOT 84    // max watcher slots per block (e==0: M*21)

typedef _Float16 half8 __attribute__((ext_vector_type(8)));
typedef float    f32x4 __attribute__((ext_vector_type(4)));

// workspace layout (fp32 elements)
#define WS_TEMB 0
#define WS_AEMB (WS_TEMB + BB*H)
#define WS_FEMB (WS_AEMB + BB*H)
#define WS_TA   (WS_FEMB + BB*H)
#define WS_TF   (WS_TA + NS*H)
#define WS_AN   (WS_TF + NS*H)
#define WS_FA   (WS_AN + NS*H)
#define WS_FLAGS (WS_FA + NS*H)   // 2 ints: [0]=floats-are-bf16, [1]=ints-are-int64

#define LOG2E  1.442695041f
#define LOG2E2 2.885390082f

__device__ static inline float bf2f(unsigned short u) {
  unsigned int i = ((unsigned int)u) << 16;
  return __builtin_bit_cast(float, i);
}
__device__ static inline unsigned short f2bf(float f) {
  unsigned int i = __builtin_bit_cast(unsigned int, f);
  i += 0x7fffu + ((i >> 16) & 1u);
  return (unsigned short)(i >> 16);
}
__device__ static inline float loadF(const void* p, size_t i, int isbf) {
  return isbf ? bf2f(((const unsigned short*)p)[i]) : ((const float*)p)[i];
}
__device__ static inline int loadI(const void* p, int i, int is64) {
  return is64 ? (int)((const unsigned int*)p)[2*(size_t)i] : ((const int*)p)[i];
}
__device__ static inline float frcp(float x) { return __builtin_amdgcn_rcpf(x); }
__device__ static inline float ex2(float x)  { return __builtin_amdgcn_exp2f(x); }
// args pre-scaled by log2e (sigm) / 2*log2e (tanh)
__device__ static inline float sigmY(float y)  { return frcp(1.f + ex2(-y)); }
__device__ static inline float tanhY(float y)  { return 1.f - 2.f*frcp(1.f + ex2(y)); }
__device__ static inline float scrub(float x) { return (x == x) ? x : 0.f; }
__device__ static inline int clampT(int v) { v = v - 1; if (v < 0) v = 0; if (v > T-1) v = T-1; return v; }

__global__ __launch_bounds__(512, 2) void lstm_scan(
    const void* __restrict__ x0_, const void* __restrict__ len0,
    const void* __restrict__ sub_ta, const void* __restrict__ sub_tf,
    const void* __restrict__ x1_, const void* __restrict__ len1,
    const void* __restrict__ sub_an,
    const void* __restrict__ x2_, const void* __restrict__ len2,
    const void* __restrict__ sub_fa,
    const void* __restrict__ Wih, const void* __restrict__ Whh,
    const void* __restrict__ bih, const void* __restrict__ bhh,
    float* __restrict__ ws)
{
  const int e      = blockIdx.y;
  const int s0     = blockIdx.x * M;
  const int tid    = threadIdx.x;
  const int lane   = tid & 63;
  const int w      = tid >> 6;     // wave 0..7, owns h-cols [16w,16w+16)
  const int lo     = lane & 15;
  const int quad   = lane >> 4;    // elementwise: my seq

  // ---- in-block dtype detection (uniform scalar loop; block (0,0) publishes for dists)
  int fbf, f64;
  {
    const unsigned int* wp = (const unsigned int*)Whh;
    int cnt = 0;
    for (int i = 0; i < 64; ++i) {
      unsigned int lo16 = wp[i] & 0xFFFFu;
      int ex = (int)((lo16 >> 7) & 0xFFu);
      cnt += (ex >= 100 && ex <= 130);
    }
    fbf = (cnt >= 40);
    const unsigned int* l = (const unsigned int*)len0;
    f64 = ((l[1] | l[3] | l[5] | l[7]) == 0u);
    if (blockIdx.x == 0 && blockIdx.y == 0 && tid == 0) {
      int* fo = (int*)(ws + WS_FLAGS); fo[0] = fbf; fo[1] = f64;
    }
  }

  const void* xin  = (e==0) ? x0_ : (e==1 ? x1_ : x2_);
  const void* lenp = (e==0) ? len0 : (e==1 ? len1 : len2);

  // h'(t) in MFMA-fragment-major order: [buf][ktile][chunk=quad'*4+seq][8 halves]
  // element h[s][c] lives at [c>>5][((c>>3)&3)*4+s][c&7]
  __shared__ __align__(16) _Float16 afr[2][4][16][8];
  __shared__ __align__(16) float2 xbf[M][T+2];            // x pairs, stride T+2
  __shared__ __align__(16) _Float16 sbuf[MAXSLOT][H];     // watcher snapshots (f16)
  __shared__ int slot_off[MAXSLOT];                       // ws offset per slot

  ((unsigned int*)afr)[tid] = 0u;                         // zero both h buffers (512 dw)
  // ---- stage x[:, :, 0:2] to LDS as f32 pairs
  for (int i = tid; i < M*T; i += 512) {
    int m = i >> 9, t = i & (T-1);
    size_t base = ((size_t)(s0+m)*T + t) * DX;
    xbf[m][t] = make_float2(loadF(xin, base + 0, fbf), loadF(xin, base + 1, fbf));
  }
  // ---- weight B-fragments: W_hh only, K=128; pre-scaled (i,f,o: log2e; g: 2*log2e)
  half8 Bf[4][4];
  const int col = w*16 + lo;
  #pragma unroll
  for (int q = 0; q < 4; ++q) {
    const float sc = (q == 2) ? LOG2E2 : LOG2E;
    const int g = q*128 + col;
    #pragma unroll
    for (int kt = 0; kt < 4; ++kt) {
      #pragma unroll
      for (int j = 0; j < 8; ++j) {
        const int k = kt*32 + quad*8 + j;
        Bf[q][kt][j] = (_Float16)(sc * loadF(Whh, (size_t)g*H + k, fbf));
      }
    }
  }
  // ---- per-lane x-weights and bias for my cell (seq=quad, col)
  float wx0[4], wx1[4], bb[4];
  #pragma unroll
  for (int q = 0; q < 4; ++q) {
    const float sc = (q == 2) ? LOG2E2 : LOG2E;
    const int g = q*128 + col;
    wx0[q] = sc * loadF(Wih, (size_t)g*2 + 0, fbf);
    wx1[q] = sc * loadF(Wih, (size_t)g*2 + 1, fbf);
    bb[q]  = sc * (loadF(bih, g, fbf) + loadF(bhh, g, fbf));
  }
  // ---- per-thread watcher slot (slot id == tid; max 84 < 512)
  const int nslots = (e == 0) ? M*21 : M*11;
  int myt = -1, mym = 0;
  if (e == 0) {
    if (tid < M*21) {
      int m = tid / 21, j = tid - m*21, sg = s0 + m;
      mym = m;
      int off;
      if (j == 0)       { myt = clampT(loadI(lenp, sg, f64));            off = WS_TEMB + sg*H; }
      else if (j <= 10) { int k = sg*10 + (j-1);  myt = clampT(loadI(sub_ta, k, f64)); off = WS_TA + k*H; }
      else              { int k = sg*10 + (j-11); myt = clampT(loadI(sub_tf, k, f64)); off = WS_TF + k*H; }
      slot_off[tid] = off;
    }
  } else {
    if (tid < M*11) {
      int m = tid / 11, j = tid - m*11, sg = s0 + m;
      mym = m;
      int off;
      if (j == 0) { myt = clampT(loadI(lenp, sg, f64)); off = (e==1 ? WS_AEMB : WS_FEMB) + sg*H; }
      else {
        int k = sg*10 + (j-1);
        if (e == 1) { myt = clampT(loadI(sub_an, k, f64)); off = WS_AN + k*H; }
        else        { myt = clampT(loadI(sub_fa, k, f64)); off = WS_FA + k*H; }
      }
      slot_off[tid] = off;
    }
  }
  __syncthreads();

  float cc = 0.f;                 // c-state for my cell (seq=quad, col)
  const int rdchunk = quad*4 + (lo & 3);                    // A-frag read chunk
  const int wrkt    = w >> 1;                               // h-write ktile
  const int wrchunk = ((w & 1)*2 + (lo >> 3))*4 + quad;     // h-write chunk
  const int wrj     = lo & 7;                               // h-write j

  for (int t = 0; t < T; ++t) {
    const int p = t & 1, qn = p ^ 1;
    // x + bias fold — independent of MFMA, overlaps A-read/MFMA latency
    float2 xv = xbf[quad][t];
    float xq[4];
    #pragma unroll
    for (int q = 0; q < 4; ++q) xq[q] = bb[q] + wx0[q]*xv.x + wx1[q]*xv.y;

    // A-fragments: 16 distinct 16B chunks, 4-lane broadcast (conflict-free)
    half8 A[4];
    #pragma unroll
    for (int kt = 0; kt < 4; ++kt)
      A[kt] = *(const half8*)&afr[p][kt][rdchunk][0];

    f32x4 G[4];
    #pragma unroll
    for (int q = 0; q < 4; ++q) G[q] = (f32x4){0.f, 0.f, 0.f, 0.f};
    #pragma unroll
    for (int kt = 0; kt < 4; ++kt)
      #pragma unroll
      for (int q = 0; q < 4; ++q)
        G[q] = __builtin_amdgcn_mfma_f32_16x16x32_f16(A[kt], Bf[q][kt], G[q], 0, 0, 0);

    // A rows 4-15 duplicate rows 0-3 => G[q][r] = gate[seq r][col] in EVERY quad.
    // My cell's gate q is G[q][quad]: pure register select, no LDS round-trip.
    float R[4];
    #pragma unroll
    for (int q = 0; q < 4; ++q) {
      float g01 = (quad & 1) ? G[q][1] : G[q][0];
      float g23 = (quad & 1) ? G[q][3] : G[q][2];
      R[q] = ((quad & 2) ? g23 : g01) + xq[q];
    }
    float si = sigmY(R[0]);
    float sf = sigmY(R[1]);
    float tg = tanhY(R[2]);
    float so = sigmY(R[3]);
    cc = sf*cc + si*tg;
    afr[qn][wrkt][wrchunk][wrj] = (_Float16)(so * tanhY(cc * LOG2E2));
    __syncthreads();
    // ---- ballot-cooperative watcher snapshots -> LDS staging (no global stores in loop)
    unsigned long long mask = __ballot(myt == t);
    while (mask) {
      int src = __ffsll((unsigned long long)mask) - 1;
      mask &= mask - 1;
      int m    = __shfl(mym, src);
      int slot = w*64 + src;           // slot id == tid of src lane
      int c0   = 2*lane;
      unsigned int pk = *(const unsigned int*)&afr[qn][c0>>5][((c0>>3)&3)*4 + m][c0&7];
      *(unsigned int*)&sbuf[slot][c0] = pk;
    }
  }
  __syncthreads();
  // ---- bulk snapshot write-out: slots * 64 dwords, coalesced
  for (int i = tid; i < nslots*64; i += 512) {
    int slot = i >> 6, c2 = i & 63;
    unsigned int pk = *(const unsigned int*)&sbuf[slot][2*c2];
    float2 v;
    v.x = (float)__builtin_bit_cast(_Float16, (unsigned short)(pk & 0xFFFFu));
    v.y = (float)__builtin_bit_cast(_Float16, (unsigned short)(pk >> 16));
    *(float2*)(ws + slot_off[slot] + 2*c2) = v;
  }
}

__global__ void dists(const float* __restrict__ ws, void* __restrict__ outv) {
  const int fbf = ((const int*)(ws + WS_FLAGS))[0];
  const int gtid = blockIdx.x*256 + threadIdx.x;
  const int widx = gtid >> 6, lane = gtid & 63;
  const float *pa, *pb;
  if (widx < 220)       { pa = ws + WS_TEMB + (size_t)widx*H;        pb = ws + WS_AEMB + (size_t)widx*H; }
  else if (widx < 440)  { int b = widx-220;  pa = ws + WS_TEMB + (size_t)b*H; pb = ws + WS_FEMB + (size_t)b*H; }
  else if (widx < 2640) { int k = widx-440;  pa = ws + WS_TA + (size_t)k*H;   pb = ws + WS_AN + (size_t)k*H; }
  else                  { int k = widx-2640; pa = ws + WS_TF + (size_t)k*H;   pb = ws + WS_FA + (size_t)k*H; }
  float d0 = pa[lane]    - pb[lane];
  float d1 = pa[lane+64] - pb[lane+64];
  float s  = scrub(d0*d0 + d1*d1);
  #pragma unroll
  for (int off = 32; off > 0; off >>= 1) s += __shfl_down(s, off, 64);
  if (lane == 0) {
    float r = __expf(-sqrtf(s));
    if (fbf) ((unsigned short*)outv)[widx] = f2bf(r);
    else     ((float*)outv)[widx] = r;
  }
}

extern "C" void kernel_launch(void* const* d_in, const int* in_sizes, int n_in,
                              void* d_out, int out_size, void* d_ws, size_t ws_size,
                              hipStream_t stream) {
  float* ws = (float*)d_ws;
  hipLaunchKernelGGL(lstm_scan, dim3(NBLK, 3), dim3(512), 0, stream,
                     d_in[0], d_in[1], d_in[2], d_in[3],
                     d_in[4], d_in[5], d_in[6],
                     d_in[7], d_in[8], d_in[9],
                     d_in[10], d_in[11], d_in[12], d_in[13], ws);
  hipLaunchKernelGGL(dists, dim3(4840*64/256), dim3(256), 0, stream, ws, d_out);
}